// Round 7
// baseline (191.769 us; speedup 1.0000x reference)
//
#include <hip/hip_runtime.h>

typedef __bf16 bf16x8 __attribute__((ext_vector_type(8)));
typedef __bf16 bf16x4 __attribute__((ext_vector_type(4)));
typedef float  f32x4  __attribute__((ext_vector_type(4)));

#define BK 64

__device__ __forceinline__ void g2l16(const void* g, void* l) {
    __builtin_amdgcn_global_load_lds((const __attribute__((address_space(1))) void*)g,
                                     (__attribute__((address_space(3))) void*)l, 16, 0, 0);
}

// Staging geometry (all gemms): [rows][BK=64] bf16 tiles in LDS, unpadded,
// 16B-unit XOR swizzle (unit ^= row&7) realized by swizzling the global
// SOURCE column (g2l writes lane-linear). Fragment read XORs back -> 0
// bank conflicts (R3-verified).

// ---------------------------------------------------------------------------
// proj: q/k/v = xb @ Wb^T + b (all bf16 in), z selects W/bias/output path.
// g2l staging + XOR swizzle; full-line LDS epilogue. (R3-verified, unchanged)
__global__ __launch_bounds__(256)
void gemm_proj(const __bf16* __restrict__ A, const __bf16* __restrict__ Wb,
               __bf16* __restrict__ qkv, const float* __restrict__ bpack)
{
    __shared__ __align__(16) __bf16 smem[128 * 128];   // 32768 B
    __bf16* As = smem;
    __bf16* Bs = smem + 128 * BK;

    const int tid  = threadIdx.x;
    const int w    = tid >> 6;
    const int lane = tid & 63;
    const int quad = lane >> 4;
    const int l16  = lane & 15;
    const int wm   = w & 1;
    const int wn   = w >> 1;

    const int m0 = blockIdx.x * 128;
    const int n0 = blockIdx.y * 128;
    const int z  = blockIdx.z;

    const __bf16* Bb   = Wb + (size_t)z * 131072;
    const float*  bias = bpack + z * 256;

    const int srow = (w << 3) + (lane >> 3);
    const int scol = ((lane & 7) ^ (lane >> 3)) << 3;
    char* ldsA = (char*)As + (size_t)w * 1024;
    char* ldsB = (char*)Bs + (size_t)w * 1024;

    const __bf16* Ag = A  + (size_t)(m0 + srow) * 256 + scol;
    const __bf16* Bg = Bb + (size_t)(n0 + srow) * 256 + scol;

    f32x4 acc[4][4] = {};

    for (int k0 = 0; k0 < 256; k0 += BK) {
        __syncthreads();
        #pragma unroll
        for (int c = 0; c < 4; c++)
            g2l16(Ag + (size_t)(c * 32) * 256 + k0, ldsA + c * 4096);
        #pragma unroll
        for (int c = 0; c < 4; c++)
            g2l16(Bg + (size_t)(c * 32) * 256 + k0, ldsB + c * 4096);
        __syncthreads();

        #pragma unroll
        for (int kk = 0; kk < BK; kk += 32) {
            const int ub = kk >> 3;
            bf16x8 a[4], b[4];
            #pragma unroll
            for (int mt = 0; mt < 4; mt++) {
                const int row = wm * 64 + mt * 16 + l16;
                const int cp  = ((quad + ub) ^ (row & 7)) << 3;
                a[mt] = *(const bf16x8*)&As[row * BK + cp];
            }
            #pragma unroll
            for (int nt = 0; nt < 4; nt++) {
                const int row = wn * 64 + nt * 16 + l16;
                const int cp  = ((quad + ub) ^ (row & 7)) << 3;
                b[nt] = *(const bf16x8*)&Bs[row * BK + cp];
            }
            #pragma unroll
            for (int mt = 0; mt < 4; mt++)
                #pragma unroll
                for (int nt = 0; nt < 4; nt++)
                    acc[mt][nt] = __builtin_amdgcn_mfma_f32_16x16x32_bf16(
                        a[mt], b[nt], acc[mt][nt], 0, 0, 0);
        }
    }

    __syncthreads();
    if (z < 2) {
        #pragma unroll
        for (int mt = 0; mt < 4; mt++) {
            const int rl = wm * 64 + mt * 16 + quad * 4;
            #pragma unroll
            for (int nt = 0; nt < 4; nt++) {
                const int cl = wn * 64 + nt * 16 + l16;
                const float bn = bias[n0 + cl];
                #pragma unroll
                for (int r = 0; r < 4; r++) {
                    const int row = rl + r;
                    smem[row * 128 + ((((cl >> 3) ^ (row & 7)) << 3) | (cl & 7))] =
                        (__bf16)(acc[mt][nt][r] + bn);
                }
            }
        }
        __syncthreads();
        __bf16* C = qkv + (size_t)z * 8388608;
        #pragma unroll
        for (int i = 0; i < 8; i++) {
            const int c   = tid + i * 256;
            const int row = c >> 4, u = c & 15;
            *(bf16x8*)&C[(size_t)(m0 + row) * 256 + n0 + u * 8] =
                *(const bf16x8*)&smem[row * 128 + ((u ^ (row & 7)) << 3)];
        }
    } else {
        #pragma unroll
        for (int mt = 0; mt < 4; mt++) {
            const int ml = wm * 64 + mt * 16 + quad * 4;
            #pragma unroll
            for (int nt = 0; nt < 4; nt++) {
                const int dl = wn * 64 + nt * 16 + l16;
                const float bn = bias[n0 + dl];
                bf16x4 pk;
                #pragma unroll
                for (int r = 0; r < 4; r++) pk[r] = (__bf16)(acc[mt][nt][r] + bn);
                *(bf16x4*)&smem[dl * 128 + ((((ml >> 3) ^ (dl & 7)) << 3) | (ml & 7))] = pk;
            }
        }
        __syncthreads();
        __bf16* C = qkv + 2 * 8388608;
        const int bidx = m0 >> 10, mbase = m0 & 1023;
        #pragma unroll
        for (int i = 0; i < 8; i++) {
            const int c  = tid + i * 256;
            const int dl = c >> 4, u = c & 15;
            *(bf16x8*)&C[(size_t)bidx * 262144 + (size_t)(n0 + dl) * 1024 + mbase + u * 8] =
                *(const bf16x8*)&smem[dl * 128 + ((u ^ (dl & 7)) << 3)];
        }
    }
}

// ---------------------------------------------------------------------------
// logits: E[b] = exp(q[b] @ k[b]^T). R3-verified form (g2l staging, 2-barrier,
// full-line LDS epilogue). Unchanged this round for attribution.
__global__ __launch_bounds__(256)
void gemm_logits(const __bf16* __restrict__ Q, const __bf16* __restrict__ Km,
                 __bf16* __restrict__ E)
{
    __shared__ __align__(16) __bf16 smem[128 * 128];   // 32768 B
    __bf16* As = smem;
    __bf16* Bs = smem + 128 * BK;

    const int tid  = threadIdx.x;
    const int w    = tid >> 6;
    const int lane = tid & 63;
    const int quad = lane >> 4;
    const int l16  = lane & 15;
    const int wm   = w & 1;
    const int wn   = w >> 1;

    const int id = blockIdx.x;
    const int x  = id & 7, s = id >> 3;
    const int z  = x + ((s >> 6) << 3);
    const int t_ = s & 63;
    const int m0 = (t_ & 7) * 128;
    const int n0 = (t_ >> 3) * 128;

    const __bf16* Ab = Q  + (size_t)z * 262144;
    const __bf16* Bb = Km + (size_t)z * 262144;

    const int srow = (w << 3) + (lane >> 3);
    const int scol = ((lane & 7) ^ (lane >> 3)) << 3;
    char* ldsA = (char*)As + (size_t)w * 1024;
    char* ldsB = (char*)Bs + (size_t)w * 1024;

    const __bf16* Ag = Ab + (size_t)(m0 + srow) * 256 + scol;
    const __bf16* Bg = Bb + (size_t)(n0 + srow) * 256 + scol;

    f32x4 acc[4][4] = {};

    for (int k0 = 0; k0 < 256; k0 += BK) {
        __syncthreads();
        #pragma unroll
        for (int c = 0; c < 4; c++)
            g2l16(Ag + (size_t)(c * 32) * 256 + k0, ldsA + c * 4096);
        #pragma unroll
        for (int c = 0; c < 4; c++)
            g2l16(Bg + (size_t)(c * 32) * 256 + k0, ldsB + c * 4096);
        __syncthreads();

        #pragma unroll
        for (int kk = 0; kk < BK; kk += 32) {
            const int ub = kk >> 3;
            bf16x8 a[4], b[4];
            #pragma unroll
            for (int mt = 0; mt < 4; mt++) {
                const int row = wm * 64 + mt * 16 + l16;
                const int cp  = ((quad + ub) ^ (row & 7)) << 3;
                a[mt] = *(const bf16x8*)&As[row * BK + cp];
            }
            #pragma unroll
            for (int nt = 0; nt < 4; nt++) {
                const int row = wn * 64 + nt * 16 + l16;
                const int cp  = ((quad + ub) ^ (row & 7)) << 3;
                b[nt] = *(const bf16x8*)&Bs[row * BK + cp];
            }
            #pragma unroll
            for (int mt = 0; mt < 4; mt++)
                #pragma unroll
                for (int nt = 0; nt < 4; nt++)
                    acc[mt][nt] = __builtin_amdgcn_mfma_f32_16x16x32_bf16(
                        a[mt], b[nt], acc[mt][nt], 0, 0, 0);
        }
    }

    __syncthreads();
    #pragma unroll
    for (int mt = 0; mt < 4; mt++) {
        const int rl = wm * 64 + mt * 16 + quad * 4;
        #pragma unroll
        for (int nt = 0; nt < 4; nt++) {
            const int cl = wn * 64 + nt * 16 + l16;
            #pragma unroll
            for (int r = 0; r < 4; r++) {
                const int row = rl + r;
                smem[row * 128 + ((((cl >> 3) ^ (row & 7)) << 3) | (cl & 7))] =
                    (__bf16)__expf(acc[mt][nt][r]);
            }
        }
    }
    __syncthreads();
    __bf16* C = E + (size_t)z * 1048576;
    #pragma unroll
    for (int i = 0; i < 8; i++) {
        const int c   = tid + i * 256;
        const int row = c >> 4, u = c & 15;
        *(bf16x8*)&C[(size_t)(m0 + row) * 1024 + n0 + u * 8] =
            *(const bf16x8*)&smem[row * 128 + ((u ^ (row & 7)) << 3)];
    }
}

// ---------------------------------------------------------------------------
// softmax_norm (R0-verified): S[n,m] = sum_b E[b,n,m]; E <- E/S in place.
// Single pass, 32 batch slices in registers. Restored so pv is pure-g2l
// (clean vmcnt counting for the pipelined loop).
__global__ __launch_bounds__(256)
void softmax_norm(__bf16* __restrict__ E)
{
    const size_t p = (size_t)blockIdx.x * 256 + threadIdx.x;
    bf16x8* E8 = (bf16x8*)E;
    bf16x8 e[32];
    #pragma unroll
    for (int b = 0; b < 32; b++) e[b] = E8[(size_t)b * 131072 + p];
    float s[8] = {0.f, 0.f, 0.f, 0.f, 0.f, 0.f, 0.f, 0.f};
    #pragma unroll
    for (int b = 0; b < 32; b++)
        #pragma unroll
        for (int j = 0; j < 8; j++) s[j] += (float)e[b][j];
    float rs[8];
    #pragma unroll
    for (int j = 0; j < 8; j++) rs[j] = __builtin_amdgcn_rcpf(s[j]);
    #pragma unroll
    for (int b = 0; b < 32; b++) {
        bf16x8 o = e[b];
        #pragma unroll
        for (int j = 0; j < 8; j++) o[j] = (__bf16)((float)o[j] * rs[j]);
        E8[(size_t)b * 131072 + p] = o;
    }
}

// ---------------------------------------------------------------------------
// pv: out[z] = attn[z] @ vT[z]^T (E pre-normalized). R7: counted-vmcnt
// 3-buffer depth-2 pipeline (T4, m201 ledger):
//   prologue: STAGE(0), STAGE(1)          [12 vmem ops]
//   iter t:   vmcnt(6)  -> stage t landed (t+1's 6 still in flight; oldest-
//                          first semantics, m135)
//             sched_barrier(0) (rule #18: stop hoisting past the asm wait)
//             s_barrier  -> every wave certified its own stage-t writes AND
//                          finished reading buf (t-1)%3 in iter t-1
//             STAGE((t+2)%3) -> WAR-safe: target last read at iter t-1
//             ds_read (t%3) + 16 MFMA
// Loads stay ~2 iters (>600cy) in flight; vmcnt never drains to 0 until the
// final iter. R4's failure was drain-0 semantics (syncthreads) + occupancy
// loss; R6 showed TLP knobs don't move pv (pinned 48us, occ pinned 36%).
// LDS 72KB (2 blocks/CU) -- pipeline replaces TLP. 128x64 tiles, grid 1024.
__global__ __launch_bounds__(256)
void gemm_pv(const __bf16* __restrict__ En, const __bf16* __restrict__ vT,
             float* __restrict__ out)
{
    __shared__ __align__(16) __bf16 smem[3 * 12288];   // 73728 B, 3 stages
    // stage s (bytes): A at s*24576 (16KB), B at s*24576+16384 (8KB)

    const int tid  = threadIdx.x;
    const int w    = tid >> 6;
    const int lane = tid & 63;
    const int quad = lane >> 4;
    const int l16  = lane & 15;
    const int wm   = w & 1;        // 64-row half
    const int wn   = w >> 1;       // 32-col half

    const int id = blockIdx.x;
    const int x  = id & 7, s = id >> 3;        // s: 0..127
    const int z  = x + ((s >> 5) << 3);        // 4 batches per XCD, sequential
    const int t_ = s & 31;
    const int m0 = (t_ & 7) * 128;             // n-row tile
    const int n0 = (t_ >> 3) * 64;             // d-col tile

    const __bf16* Eb = En + (size_t)z * 1048576;
    const __bf16* Vb = vT + (size_t)z * 262144;
    float*        Ob = out + (size_t)z * 262144;

    const int srow = (w << 3) + (lane >> 3);
    const int scol = ((lane & 7) ^ (lane >> 3)) << 3;

    const __bf16* Ag = Eb + (size_t)(m0 + srow) * 1024 + scol;
    const __bf16* Bg = Vb + (size_t)(n0 + srow) * 1024 + scol;

    f32x4 acc[4][2] = {};

    // stage issue: 4 A-rows-groups + 2 B = 6 vmem ops per thread
    auto STAGE = [&](int buf, int k0) {
        char* base = (char*)smem + buf * 24576;
        #pragma unroll
        for (int c = 0; c < 4; c++)
            g2l16(Ag + (size_t)(c * 32) * 1024 + k0, base + w * 1024 + c * 4096);
        #pragma unroll
        for (int c = 0; c < 2; c++)
            g2l16(Bg + (size_t)(c * 32) * 1024 + k0, base + 16384 + w * 1024 + c * 4096);
    };

    STAGE(0, 0);
    STAGE(1, 64);

    for (int t = 0; t < 16; t++) {
        if (t < 15) {
            asm volatile("s_waitcnt vmcnt(6)" ::: "memory");
        } else {
            asm volatile("s_waitcnt vmcnt(0)" ::: "memory");
        }
        __builtin_amdgcn_sched_barrier(0);
        __builtin_amdgcn_s_barrier();

        if (t + 2 < 16) STAGE((t + 2) % 3, (t + 2) * BK);

        const __bf16* As = smem + (t % 3) * 12288;
        const __bf16* Bs = As + 8192;
        #pragma unroll
        for (int kk = 0; kk < BK; kk += 32) {
            const int ub = kk >> 3;
            bf16x8 a[4], b[2];
            #pragma unroll
            for (int mt = 0; mt < 4; mt++) {
                const int row = wm * 64 + mt * 16 + l16;
                const int cp  = ((quad + ub) ^ (row & 7)) << 3;
                a[mt] = *(const bf16x8*)&As[row * BK + cp];
            }
            #pragma unroll
            for (int nt = 0; nt < 2; nt++) {
                const int row = wn * 32 + nt * 16 + l16;
                const int cp  = ((quad + ub) ^ (row & 7)) << 3;
                b[nt] = *(const bf16x8*)&Bs[row * BK + cp];
            }
            #pragma unroll
            for (int mt = 0; mt < 4; mt++)
                #pragma unroll
                for (int nt = 0; nt < 2; nt++)
                    acc[mt][nt] = __builtin_amdgcn_mfma_f32_16x16x32_bf16(
                        a[mt], b[nt], acc[mt][nt], 0, 0, 0);
        }
    }

    // fp32 direct stores: 16 lanes x 4B = full 64B lines. (R3-verified)
    #pragma unroll
    for (int mt = 0; mt < 4; mt++) {
        const int mb = m0 + wm * 64 + mt * 16 + quad * 4;
        #pragma unroll
        for (int nt = 0; nt < 2; nt++) {
            const int n = n0 + wn * 32 + nt * 16 + l16;
            #pragma unroll
            for (int r = 0; r < 4; r++)
                Ob[(size_t)(mb + r) * 256 + n] = acc[mt][nt][r];
        }
    }
}

// ---------------------------------------------------------------------------
// One launch: x -> bf16, Wq/Wk/Wv -> bf16, pack 3 fp32 biases.
__global__ __launch_bounds__(256)
void cvt_all(const float* __restrict__ x,
             const float* __restrict__ Wq, const float* __restrict__ Wk,
             const float* __restrict__ Wv,
             const float* __restrict__ bq, const float* __restrict__ bk,
             const float* __restrict__ bv,
             __bf16* __restrict__ xb, __bf16* __restrict__ Wqb,
             float* __restrict__ bpack)
{
    const int i = blockIdx.x * 256 + threadIdx.x;
    if (i < 1073152) {
        const float* s; __bf16* d; int off;
        if (i < 1048576)      { s = x;  d = xb;            off = i; }
        else if (i < 1056768) { s = Wq; d = Wqb;           off = i - 1048576; }
        else if (i < 1064960) { s = Wk; d = Wqb + 131072;  off = i - 1056768; }
        else                  { s = Wv; d = Wqb + 262144;  off = i - 1064960; }
        const float4* s4 = (const float4*)s;
        const float4 f0 = s4[off * 2], f1 = s4[off * 2 + 1];
        bf16x8 o;
        o[0] = (__bf16)f0.x; o[1] = (__bf16)f0.y; o[2] = (__bf16)f0.z; o[3] = (__bf16)f0.w;
        o[4] = (__bf16)f1.x; o[5] = (__bf16)f1.y; o[6] = (__bf16)f1.z; o[7] = (__bf16)f1.w;
        ((bf16x8*)d)[off] = o;
    } else if (i < 1073344) {
        const int j = i - 1073152;
        const int sel = j >> 6, jj = j & 63;
        const float* s = sel == 0 ? bq : (sel == 1 ? bk : bv);
        ((float4*)bpack)[j] = ((const float4*)s)[jj];
    }
}

extern "C" void kernel_launch(void* const* d_in, const int* in_sizes, int n_in,
                              void* d_out, int out_size, void* d_ws, size_t ws_size,
                              hipStream_t stream)
{
    const float* x  = (const float*)d_in[0];
    const float* Wq = (const float*)d_in[1];
    const float* bq = (const float*)d_in[2];
    const float* Wk = (const float*)d_in[3];
    const float* bk = (const float*)d_in[4];
    const float* Wv = (const float*)d_in[5];
    const float* bv = (const float*)d_in[6];
    float* out = (float*)d_out;

    // Workspace layout (bytes):
    //   [2M,18M)   xb  bf16 (32768x256)
    //   [18M,34M)  q   bf16 \
    //   [34M,50M)  k   bf16  } stride 8388608 elems
    //   [50M,66M)  vT  bf16 (32,256,1024) /
    //   [66M,130M) E   bf16 (32,1024,1024), normalized in place
    //   [130M,..)  Wqb bf16 (3 x 65536 elems at 131072-elem stride) + bpack
    char* ws = (char*)d_ws;
    __bf16* xb   = (__bf16*)(ws + (2u  << 20));
    __bf16* qkv  = (__bf16*)(ws + (18u << 20));
    __bf16* E    = (__bf16*)(ws + (66u << 20));
    __bf16* Wqb  = (__bf16*)(ws + (130u << 20));
    float*  bpack = (float*)(ws + (130u << 20) + (1u << 20));

    // 1) converts + bias pack
    cvt_all<<<4194, 256, 0, stream>>>(x, Wq, Wk, Wv, bq, bk, bv, xb, Wqb, bpack);

    // 2) q/k/v projections
    gemm_proj<<<dim3(256, 2, 3), 256, 0, stream>>>(xb, Wqb, qkv, bpack);

    // 3) E[b] = exp(q[b] @ k[b]^T), XCD-sequential flat grid
    gemm_logits<<<2048, 256, 0, stream>>>(qkv, qkv + 8388608, E);

    // 4) batch-axis softmax normalize in place (E <- E / sum_b E)
    softmax_norm<<<512, 256, 0, stream>>>(E);

    // 5) out[b] = attn[b] @ vT[b]^T, counted-vmcnt depth-2 pipeline
    gemm_pv<<<1024, 256, 0, stream>>>(E, qkv + 2 * 8388608, out);
}